// Round 11
// baseline (98.704 us; speedup 1.0000x reference)
//
#include <hip/hip_runtime.h>
#include <hip/hip_bf16.h>
#include <stdint.h>

#define NB 2
#define LQ 2048
#define DMODEL 1024
#define NH 8
#define DH 128
#define KWIN 64

typedef __attribute__((ext_vector_type(8))) short short8;
typedef __attribute__((ext_vector_type(4))) float f32x4;

#define AS1 __attribute__((address_space(1)))
#define AS3 __attribute__((address_space(3)))

__device__ __forceinline__ ushort f2bf(float f) {
  uint u = __float_as_uint(f);
  return (ushort)((u + 0x7fffu + ((u >> 16) & 1u)) >> 16);
}

// ---------------- merged f32 -> bf16 conversion (7 arrays, one launch) ----------------
__global__ void cvt_all(const float4* __restrict__ q, const float4* __restrict__ k,
                        const float4* __restrict__ v, const float4* __restrict__ wq,
                        const float4* __restrict__ wk, const float4* __restrict__ wv,
                        const float4* __restrict__ wc, ushort4* __restrict__ dst) {
  const int n4in = (NB * LQ * DMODEL) / 4;   // 2^20
  const int n4w = (NH * DH * DMODEL) / 4;    // 2^18
  const int total = 3 * n4in + 4 * n4w;
  const int stride = gridDim.x * blockDim.x;
  for (int i = blockIdx.x * blockDim.x + threadIdx.x; i < total; i += stride) {
    const float4* src;
    int off;
    if (i < 3 * n4in) {
      const int r = i >> 20;
      off = i & (n4in - 1);
      src = (r == 0) ? q : ((r == 1) ? k : v);
    } else {
      const int j = i - 3 * n4in;
      const int r = j >> 18;
      off = j & (n4w - 1);
      src = (r == 0) ? wq : ((r == 1) ? wk : ((r == 2) ? wv : wc));
    }
    float4 x = src[off];
    dst[i] = make_ushort4(f2bf(x.x), f2bf(x.y), f2bf(x.z), f2bf(x.w));
  }
}

// ====== QKV GEMM: 256x64 tile, BK=32, 768 blocks = 3/CU exact (util fix), 2-phase ======
// 4 waves, per-wave 64x64 out (4x4 16^2 frags). LDS 40KB dbuf. m97 ratio: 8 ds_read_b128
// : 16 MFMA per wave-iter. All waves share the B-tile reads (same addr -> broadcast).
// Chunked-bijective XCD swizzle: XCD x processes contiguous tiles -> A-panel L2-reuse 16x.
__global__ __launch_bounds__(256, 3) void gemm_qkv_tall(
    const ushort* __restrict__ A0, const ushort* __restrict__ B0,
    const float* __restrict__ c0, ushort* __restrict__ D0,
    const ushort* __restrict__ A1, const ushort* __restrict__ B1,
    const float* __restrict__ c1, ushort* __restrict__ D1,
    const ushort* __restrict__ A2, const ushort* __restrict__ B2,
    const float* __restrict__ c2, ushort* __restrict__ D2,
    int M, int N, int Kd) {
  const int gx = gridDim.x, gy = gridDim.y;      // 16, 16
  const int nblk = gx * gy * gridDim.z;          // 768
  const int fid = (blockIdx.z * gy + blockIdx.y) * gx + blockIdx.x;
  const int nid = (fid & 7) * (nblk >> 3) + (fid >> 3);  // XCD-contiguous tile runs
  const int z = nid / (gx * gy);
  const int rem = nid % (gx * gy);
  const int m0 = (rem / gx) * 256;
  const int n0 = (rem % gx) * 64;

  const ushort* A = (z == 0) ? A0 : ((z == 1) ? A1 : A2);
  const ushort* Bt = (z == 0) ? B0 : ((z == 1) ? B1 : B2);
  const float* bias = (z == 0) ? c0 : ((z == 1) ? c1 : c2);
  ushort* Cv = (z == 0) ? D0 : ((z == 1) ? D1 : D2);

  __shared__ ushort As[2][256 * 32];  // 16 KB each
  __shared__ ushort Bs[2][64 * 32];   // 4 KB each

  const int tid = threadIdx.x;
  const int wave = tid >> 6, lane = tid & 63;
  const int lrow = lane & 15, kgrp = lane >> 4;

  // staging: A chunk c = j*256+tid (row=c>>2, k8=(c&3)*8), 4/thread; B chunk tid, 1/thread
  const ushort* gA[4];
#pragma unroll
  for (int j = 0; j < 4; ++j) {
    const int c = j * 256 + tid;
    gA[j] = A + (size_t)(m0 + (c >> 2)) * Kd + (c & 3) * 8;
  }
  const ushort* gB = Bt + (size_t)(n0 + (tid >> 2)) * Kd + (tid & 3) * 8;

  auto stage = [&](int buf, int kt) {
#pragma unroll
    for (int j = 0; j < 4; ++j)
      __builtin_amdgcn_global_load_lds((const AS1 void*)(gA[j] + kt),
                                       (AS3 void*)(As[buf] + (j * 256 + tid) * 8), 16, 0, 0);
    __builtin_amdgcn_global_load_lds((const AS1 void*)(gB + kt),
                                     (AS3 void*)(Bs[buf] + tid * 8), 16, 0, 0);
  };

  f32x4 acc[4][4] = {};
  auto compute = [&](int buf) {
    short8 af[4], bfr[4];
#pragma unroll
    for (int mi = 0; mi < 4; ++mi)
      af[mi] = *(const short8*)(As[buf] + (wave * 64 + mi * 16 + lrow) * 32 + kgrp * 8);
#pragma unroll
    for (int ni = 0; ni < 4; ++ni)
      bfr[ni] = *(const short8*)(Bs[buf] + (ni * 16 + lrow) * 32 + kgrp * 8);
#pragma unroll
    for (int mi = 0; mi < 4; ++mi)
#pragma unroll
      for (int ni = 0; ni < 4; ++ni)
        acc[mi][ni] = __builtin_amdgcn_mfma_f32_16x16x32_bf16(af[mi], bfr[ni], acc[mi][ni], 0, 0, 0);
  };

  const int nt = Kd >> 5;  // 32
  stage(0, 0);
  __syncthreads();
  int cur = 0;
  for (int it = 0; it < nt - 1; ++it) {
    stage(cur ^ 1, (it + 1) << 5);
    compute(cur);
    __syncthreads();
    cur ^= 1;
  }
  compute(cur);

  // epilogue: C/D layout col=lane&15, row=(lane>>4)*4+j
  const int rbase = m0 + wave * 64;
  float bv[4];
#pragma unroll
  for (int ni = 0; ni < 4; ++ni) bv[ni] = bias[n0 + ni * 16 + lrow];
#pragma unroll
  for (int mi = 0; mi < 4; ++mi)
#pragma unroll
    for (int ni = 0; ni < 4; ++ni) {
      const int col = n0 + ni * 16 + lrow;
#pragma unroll
      for (int j = 0; j < 4; ++j)
        Cv[(size_t)(rbase + mi * 16 + kgrp * 4 + j) * N + col] = f2bf(acc[mi][ni][j] + bv[ni]);
    }
}

// ========= out-proj GEMM: 64x64 tile, BK=32, 1024 blocks = 4/CU (R10, passed) =========
__global__ __launch_bounds__(256, 4) void gemm_out3(
    const ushort* __restrict__ A, const ushort* __restrict__ Bt,
    const float* __restrict__ bias, float* __restrict__ Cv, int M, int N, int Kd) {
  const int gx = gridDim.x;  // 16
  const int nblk = gx * gridDim.y;
  const int fid = blockIdx.y * gx + blockIdx.x;
  const int nid = (fid & 7) * (nblk >> 3) + (fid >> 3);
  const int m0 = (nid / gx) * 64;
  const int n0 = (nid % gx) * 64;

  __shared__ ushort As[2][64 * 32];
  __shared__ ushort Bs[2][64 * 32];

  const int tid = threadIdx.x;
  const int wave = tid >> 6, lane = tid & 63;
  const int wmO = wave >> 1, wnO = wave & 1;
  const int lrow = lane & 15, kgrp = lane >> 4;

  const ushort* gA = A + (size_t)(m0 + (tid >> 2)) * Kd + (tid & 3) * 8;
  const ushort* gB = Bt + (size_t)(n0 + (tid >> 2)) * Kd + (tid & 3) * 8;

  auto stage = [&](int buf, int kt) {
    __builtin_amdgcn_global_load_lds((const AS1 void*)(gA + kt),
                                     (AS3 void*)(As[buf] + tid * 8), 16, 0, 0);
    __builtin_amdgcn_global_load_lds((const AS1 void*)(gB + kt),
                                     (AS3 void*)(Bs[buf] + tid * 8), 16, 0, 0);
  };

  f32x4 acc[2][2] = {};
  auto compute = [&](int buf) {
    short8 af[2], bfr[2];
#pragma unroll
    for (int mi = 0; mi < 2; ++mi)
      af[mi] = *(const short8*)(As[buf] + (wmO * 32 + mi * 16 + lrow) * 32 + kgrp * 8);
#pragma unroll
    for (int ni = 0; ni < 2; ++ni)
      bfr[ni] = *(const short8*)(Bs[buf] + (wnO * 32 + ni * 16 + lrow) * 32 + kgrp * 8);
#pragma unroll
    for (int mi = 0; mi < 2; ++mi)
#pragma unroll
      for (int ni = 0; ni < 2; ++ni)
        acc[mi][ni] = __builtin_amdgcn_mfma_f32_16x16x32_bf16(af[mi], bfr[ni], acc[mi][ni], 0, 0, 0);
  };

  const int nt = Kd >> 5;  // 32
  stage(0, 0);
  __syncthreads();
  int cur = 0;
  for (int it = 0; it < nt - 1; ++it) {
    stage(cur ^ 1, (it + 1) << 5);
    compute(cur);
    __syncthreads();
    cur ^= 1;
  }
  compute(cur);

  const int cbase = n0 + wnO * 32;
  const int rbase = m0 + wmO * 32;
  float bv[2];
#pragma unroll
  for (int ni = 0; ni < 2; ++ni) bv[ni] = bias[cbase + ni * 16 + lrow];
#pragma unroll
  for (int mi = 0; mi < 2; ++mi)
#pragma unroll
    for (int ni = 0; ni < 2; ++ni) {
      const int col = cbase + ni * 16 + lrow;
#pragma unroll
      for (int j = 0; j < 4; ++j)
        Cv[(size_t)(rbase + mi * 16 + kgrp * 4 + j) * N + col] = acc[mi][ni][j] + bv[ni];
    }
}

// ---------------- banded attention via residue-class MFMA flash (frozen) ----------------
__global__ __launch_bounds__(128) void banded_attn_mfma(
    const ushort* __restrict__ qp, const ushort* __restrict__ kp,
    const ushort* __restrict__ vp, ushort* __restrict__ ao) {
  __shared__ ushort Qs[32 * 128];
  __shared__ ushort Ks[96 * 128];
  __shared__ ushort Vs[112 * 128];
  __shared__ ushort Ps[2][16 * 104];
  __shared__ ushort Os[2][16 * 128];

  const int tid = threadIdx.x;
  const int wv = tid >> 6;
  const int lane = tid & 63;
  const int lrow = lane & 15, kgrp = lane >> 4;

  const int blk = blockIdx.x;
  const int chunk = blk & 63;
  const int h = (blk >> 6) & 7;
  const int b = blk >> 9;
  const int sh = h >> 1;
  const int dil = 1 << sh;
  const int Ld = LQ >> sh;
  const int rres = chunk >> (6 - sh);
  const int tile = chunk & ((64 >> sh) - 1);
  const int t0 = tile << 5;
  const int p0 = t0 - 32;

  const size_t headoff = (size_t)h * DH;
  const size_t bbase = (size_t)b * LQ * (NH * DH);

  const int srow = lane >> 4;
  const int sc = lane & 15;
  for (int it = wv; it < 60; it += 2) {
    int rbase, pstart;
    const ushort* g;
    ushort* ld;
    if (it < 8) {
      rbase = it * 4; pstart = t0; g = qp; ld = Qs;
    } else if (it < 32) {
      rbase = (it - 8) * 4; pstart = p0; g = kp; ld = Ks;
    } else {
      rbase = (it - 32) * 4; pstart = p0; g = vp; ld = Vs;
    }
    int row = rbase + srow;
    int key = (row ^ (row >> 3)) & 7;
    int cs = sc ^ key;
    int t = pstart + row;
    t = t < 0 ? 0 : (t >= Ld ? Ld - 1 : t);
    int l = rres + t * dil;
    const ushort* src = g + bbase + (size_t)l * (NH * DH) + headoff + cs * 8;
    __builtin_amdgcn_global_load_lds((const AS1 void*)src,
                                     (AS3 void*)(ld + rbase * 128), 16, 0, 0);
  }
  __syncthreads();

  const int iblk = wv << 4;
  f32x4 accs[5] = {};
#pragma unroll
  for (int ks = 0; ks < 4; ++ks) {
    const int qrow = iblk + lrow;
    const int qslot = (ks * 4 + kgrp) ^ ((qrow ^ (qrow >> 3)) & 7);
    short8 qf = *(const short8*)(Qs + qrow * 128 + qslot * 8);
#pragma unroll
    for (int t = 0; t < 5; ++t) {
      const int krow = (wv + t) * 16 + lrow;
      const int kslot = (ks * 4 + kgrp) ^ ((krow ^ (krow >> 3)) & 7);
      short8 kf = *(const short8*)(Ks + krow * 128 + kslot * 8);
      accs[t] = __builtin_amdgcn_mfma_f32_16x16x32_bf16(qf, kf, accs[t], 0, 0, 0);
    }
  }

  float dens[4];
#pragma unroll
  for (int j = 0; j < 4; ++j) {
    const int i_b = iblk + kgrp * 4 + j;
    float mj = -1e30f;
#pragma unroll
    for (int t = 0; t < 5; ++t) {
      const int jj = (wv + t) * 16 + lrow;
      const int p = p0 + jj;
      const bool ok = (jj >= i_b + 1) && (jj <= i_b + 64) && (p >= 0) && (p < Ld);
      float v = ok ? accs[t][j] : -1e30f;
      accs[t][j] = v;
      mj = fmaxf(mj, v);
    }
#pragma unroll
    for (int off = 1; off < 16; off <<= 1) mj = fmaxf(mj, __shfl_xor(mj, off));
    float dj = 0.f;
#pragma unroll
    for (int t = 0; t < 5; ++t) {
      float e = __expf(accs[t][j] - mj);
      accs[t][j] = e;
      dj += e;
    }
#pragma unroll
    for (int off = 1; off < 16; off <<= 1) dj += __shfl_xor(dj, off);
    dens[j] = dj;
  }

  ushort* Pw = Ps[wv];
#pragma unroll
  for (int j = 0; j < 4; ++j) {
    const int prow = kgrp * 4 + j;
#pragma unroll
    for (int t = 0; t < 5; ++t) Pw[prow * 104 + t * 16 + lrow] = f2bf(accs[t][j]);
    Pw[prow * 104 + 80 + lrow] = 0;
  }

  f32x4 accv[8] = {};
#pragma unroll
  for (int ks = 0; ks < 3; ++ks) {
    short8 pf = *(const short8*)(Pw + lrow * 104 + ks * 32 + kgrp * 8);
#pragma unroll
    for (int dt = 0; dt < 8; ++dt) {
      short8 vf;
#pragma unroll
      for (int rr = 0; rr < 8; ++rr) {
        const int vrow = iblk + ks * 32 + kgrp * 8 + rr;
        const int d = dt * 16 + lrow;
        const int slot = (d >> 3) ^ ((vrow ^ (vrow >> 3)) & 7);
        vf[rr] = (short)Vs[vrow * 128 + slot * 8 + (d & 7)];
      }
      accv[dt] = __builtin_amdgcn_mfma_f32_16x16x32_bf16(pf, vf, accv[dt], 0, 0, 0);
    }
  }

  ushort* Ow = Os[wv];
#pragma unroll
  for (int j = 0; j < 4; ++j) {
    const float inv = 1.f / dens[j];
    const int orow = kgrp * 4 + j;
#pragma unroll
    for (int dt = 0; dt < 8; ++dt)
      Ow[orow * 128 + dt * 16 + lrow] = f2bf(accv[dt][j] * inv);
  }
#pragma unroll
  for (int pass = 0; pass < 4; ++pass) {
    const int i_loc = pass * 4 + srow;
    const int tq = t0 + iblk + i_loc;
    const int l = rres + tq * dil;
    short8 vvv = *(const short8*)(Ow + i_loc * 128 + sc * 8);
    *(short8*)(ao + bbase + (size_t)l * (NH * DH) + headoff + sc * 8) = vvv;
  }
}

// ---------------- launch ----------------
extern "C" void kernel_launch(void* const* d_in, const int* in_sizes, int n_in,
                              void* d_out, int out_size, void* d_ws, size_t ws_size,
                              hipStream_t stream) {
  const float* q = (const float*)d_in[0];
  const float* k = (const float*)d_in[1];
  const float* v = (const float*)d_in[2];
  const float* Wq = (const float*)d_in[3];
  const float* bq = (const float*)d_in[4];
  const float* Wk = (const float*)d_in[5];
  const float* bk = (const float*)d_in[6];
  const float* Wv = (const float*)d_in[7];
  const float* bv = (const float*)d_in[8];
  const float* Wc = (const float*)d_in[9];
  const float* bc = (const float*)d_in[10];

  const size_t NIN = (size_t)NB * LQ * DMODEL;
  const size_t NW = (size_t)NH * DH * DMODEL;

  ushort* qin = (ushort*)d_ws;
  ushort* kin = qin + NIN;
  ushort* vin = kin + NIN;
  ushort* wqb = vin + NIN;
  ushort* wkb = wqb + NW;
  ushort* wvb = wkb + NW;
  ushort* wcb = wvb + NW;
  ushort* qp = wcb + NW;
  ushort* kp = qp + NIN;
  ushort* vp = kp + NIN;
  ushort* aob = vp + NIN;

  hipLaunchKernelGGL(cvt_all, dim3(2048), dim3(256), 0, stream,
                     (const float4*)q, (const float4*)k, (const float4*)v,
                     (const float4*)Wq, (const float4*)Wk, (const float4*)Wv,
                     (const float4*)Wc, (ushort4*)qin);

  dim3 g1(DMODEL / 64, (NB * LQ) / 256, 3);  // 16 x 16 x 3 = 768 blocks = 3/CU exact
  hipLaunchKernelGGL(gemm_qkv_tall, g1, dim3(256), 0, stream,
                     qin, wqb, bq, qp,
                     kin, wkb, bk, kp,
                     vin, wvb, bv, vp,
                     NB * LQ, DMODEL, DMODEL);

  hipLaunchKernelGGL(banded_attn_mfma, dim3(NB * NH * 64), dim3(128), 0, stream,
                     qp, kp, vp, aob);

  dim3 g2(DMODEL / 64, (NB * LQ) / 64);  // 16 x 64 = 1024 blocks
  hipLaunchKernelGGL(gemm_out3, g2, dim3(256), 0, stream,
                     aob, wcb, bc, (float*)d_out, NB * LQ, DMODEL, DMODEL);
}

// Round 13
// 93.148 us; speedup vs baseline: 1.0596x; 1.0596x over previous
//
#include <hip/hip_runtime.h>
#include <hip/hip_bf16.h>
#include <stdint.h>

#define NB 2
#define LQ 2048
#define DMODEL 1024
#define NH 8
#define DH 128
#define KWIN 64

typedef __attribute__((ext_vector_type(8))) short short8;
typedef __attribute__((ext_vector_type(4))) float f32x4;

#define AS1 __attribute__((address_space(1)))
#define AS3 __attribute__((address_space(3)))

__device__ __forceinline__ ushort f2bf(float f) {
  uint u = __float_as_uint(f);
  return (ushort)((u + 0x7fffu + ((u >> 16) & 1u)) >> 16);
}

// ---------------- merged f32 -> bf16 conversion (7 arrays, one launch) ----------------
__global__ void cvt_all(const float4* __restrict__ q, const float4* __restrict__ k,
                        const float4* __restrict__ v, const float4* __restrict__ wq,
                        const float4* __restrict__ wk, const float4* __restrict__ wv,
                        const float4* __restrict__ wc, ushort4* __restrict__ dst) {
  const int n4in = (NB * LQ * DMODEL) / 4;   // 2^20
  const int n4w = (NH * DH * DMODEL) / 4;    // 2^18
  const int total = 3 * n4in + 4 * n4w;
  const int stride = gridDim.x * blockDim.x;
  for (int i = blockIdx.x * blockDim.x + threadIdx.x; i < total; i += stride) {
    const float4* src;
    int off;
    if (i < 3 * n4in) {
      const int r = i >> 20;
      off = i & (n4in - 1);
      src = (r == 0) ? q : ((r == 1) ? k : v);
    } else {
      const int j = i - 3 * n4in;
      const int r = j >> 18;
      off = j & (n4w - 1);
      src = (r == 0) ? wq : ((r == 1) ? wk : ((r == 2) ? wv : wc));
    }
    float4 x = src[off];
    dst[i] = make_ushort4(f2bf(x.x), f2bf(x.y), f2bf(x.z), f2bf(x.w));
  }
}

// ================= QKV GEMM: 256x256, BK=64, 8-phase (R8/R10, measured best) =================
__global__ __launch_bounds__(512, 2) void gemm256_8p(
    const ushort* __restrict__ A0p, const ushort* __restrict__ B0p,
    const float* __restrict__ c0, ushort* __restrict__ D0,
    const ushort* __restrict__ A1p, const ushort* __restrict__ B1p,
    const float* __restrict__ c1, ushort* __restrict__ D1,
    const ushort* __restrict__ A2p, const ushort* __restrict__ B2p,
    const float* __restrict__ c2, ushort* __restrict__ D2,
    int M, int N, int Kd) {
  const int gx = gridDim.x, gy = gridDim.y;
  const int nblk = gx * gy * gridDim.z;
  const int fid = (blockIdx.z * gy + blockIdx.y) * gx + blockIdx.x;
  const int nid = (fid & 7) * (nblk >> 3) + (fid >> 3);
  const int z = nid / (gx * gy);
  const int rem = nid % (gx * gy);
  const int m0 = (rem / gx) * 256;
  const int n0 = (rem % gx) * 256;

  const ushort* A = (z == 0) ? A0p : ((z == 1) ? A1p : A2p);
  const ushort* Bt = (z == 0) ? B0p : ((z == 1) ? B1p : B2p);
  const float* bias = (z == 0) ? c0 : ((z == 1) ? c1 : c2);
  ushort* Cv = (z == 0) ? D0 : ((z == 1) ? D1 : D2);

  __shared__ ushort LDS[2][32768];

  const int tid = threadIdx.x;
  const int wave = tid >> 6, lane = tid & 63;
  const int wm = wave >> 2, wn = wave & 3;
  const int lrow = lane & 15, kgrp = lane >> 4;

  int offA[2][2], offB[2][2];
#pragma unroll
  for (int u = 0; u < 2; ++u)
#pragma unroll
    for (int j = 0; j < 2; ++j) {
      const int idx = j * 512 + tid;
      const int s = idx >> 3, c = idx & 7;
      const int cs = c ^ (s & 7);
      const int rA = ((s >> 6) << 7) | (u << 6) | (s & 63);
      const int rB = ((s >> 5) << 6) | (u << 5) | (s & 31);
      offA[u][j] = (m0 + rA) * Kd + cs * 8;
      offB[u][j] = (n0 + rB) * Kd + cs * 8;
    }

  auto STAGEA = [&](int bufb, int u, int T) {
    ushort* dst = &LDS[bufb][u * 8192];
#pragma unroll
    for (int j = 0; j < 2; ++j)
      __builtin_amdgcn_global_load_lds((const AS1 void*)(A + offA[u][j] + T * 64),
                                       (AS3 void*)(dst + (j * 512 + tid) * 8), 16, 0, 0);
  };
  auto STAGEB = [&](int bufb, int u, int T) {
    ushort* dst = &LDS[bufb][16384 + u * 8192];
#pragma unroll
    for (int j = 0; j < 2; ++j)
      __builtin_amdgcn_global_load_lds((const AS1 void*)(Bt + offB[u][j] + T * 64),
                                       (AS3 void*)(dst + (j * 512 + tid) * 8), 16, 0, 0);
  };

  const int sAb = (wm * 64 + lrow) * 64;
  const int sBb = (wn * 32 + lrow) * 64;
  int xk[2];
#pragma unroll
  for (int ks = 0; ks < 2; ++ks) xk[ks] = ((ks * 4 + kgrp) ^ (lrow & 7)) * 8;

  short8 af[4][2], bf[2][2][2];
  f32x4 acc[8][4] = {};

  auto RDA = [&](int bufb, int mh) {
#pragma unroll
    for (int mi = 0; mi < 4; ++mi)
#pragma unroll
      for (int ks = 0; ks < 2; ++ks)
        af[mi][ks] = *(const short8*)(&LDS[bufb][mh * 8192 + sAb + mi * 1024 + xk[ks]]);
  };
  auto RDB = [&](int bufb, int nh) {
#pragma unroll
    for (int ni = 0; ni < 2; ++ni)
#pragma unroll
      for (int ks = 0; ks < 2; ++ks)
        bf[nh][ni][ks] =
            *(const short8*)(&LDS[bufb][16384 + nh * 8192 + sBb + ni * 1024 + xk[ks]]);
  };
  auto MM = [&](int mh, int nh) {
    __builtin_amdgcn_s_setprio(1);
#pragma unroll
    for (int mi = 0; mi < 4; ++mi)
#pragma unroll
      for (int ni = 0; ni < 2; ++ni)
#pragma unroll
        for (int ks = 0; ks < 2; ++ks)
          acc[mh * 4 + mi][nh * 2 + ni] = __builtin_amdgcn_mfma_f32_16x16x32_bf16(
              af[mi][ks], bf[nh][ni][ks], acc[mh * 4 + mi][nh * 2 + ni], 0, 0, 0);
    __builtin_amdgcn_s_setprio(0);
  };

#define LGKM0()                                        \
  asm volatile("s_waitcnt lgkmcnt(0)" ::: "memory");   \
  __builtin_amdgcn_sched_barrier(0)
#define BAR() __builtin_amdgcn_s_barrier()

  const int NKT = Kd >> 6;
  const int NIT = NKT >> 1;

  STAGEA(0, 0, 0); STAGEB(0, 0, 0); STAGEA(0, 1, 0); STAGEB(0, 1, 0);
  STAGEA(1, 0, 1); STAGEB(1, 0, 1);
  asm volatile("s_waitcnt vmcnt(4)" ::: "memory");
  __builtin_amdgcn_sched_barrier(0);
  BAR();

  for (int i = 0; i < NIT; ++i) {
    const int ta = 2 * i, tb = ta + 1;
    const bool sA = (ta + 2) < NKT, sB = (tb + 2) < NKT;
    RDA(0, 0); RDB(0, 0);
    STAGEA(1, 1, tb);
    BAR(); LGKM0(); MM(0, 0); BAR();
    RDB(0, 1);
    STAGEB(1, 1, tb);
    BAR(); LGKM0(); MM(0, 1); BAR();
    RDA(0, 1);
    if (sA) STAGEA(0, 0, ta + 2);
    BAR(); LGKM0(); MM(1, 0); BAR();
    if (sA) STAGEB(0, 0, ta + 2);
    MM(1, 1);
    if (sA) asm volatile("s_waitcnt vmcnt(4)" ::: "memory");
    else    asm volatile("s_waitcnt vmcnt(0)" ::: "memory");
    __builtin_amdgcn_sched_barrier(0);
    BAR();
    RDA(1, 0); RDB(1, 0);
    if (sA) STAGEA(0, 1, ta + 2);
    BAR(); LGKM0(); MM(0, 0); BAR();
    RDB(1, 1);
    if (sA) STAGEB(0, 1, ta + 2);
    BAR(); LGKM0(); MM(0, 1); BAR();
    RDA(1, 1);
    if (sB) STAGEA(1, 0, tb + 2);
    BAR(); LGKM0(); MM(1, 0); BAR();
    if (sB) STAGEB(1, 0, tb + 2);
    MM(1, 1);
    if (sB) asm volatile("s_waitcnt vmcnt(4)" ::: "memory");
    else    asm volatile("s_waitcnt vmcnt(0)" ::: "memory");
    __builtin_amdgcn_sched_barrier(0);
    BAR();
  }
#undef LGKM0
#undef BAR

  const int cbase = n0 + wn * 64;
  const int rbase = m0 + wm * 128;
  float bv[4];
#pragma unroll
  for (int n = 0; n < 4; ++n) bv[n] = bias[cbase + n * 16 + lrow];
#pragma unroll
  for (int m = 0; m < 8; ++m)
#pragma unroll
    for (int n = 0; n < 4; ++n) {
      const int col = cbase + n * 16 + lrow;
#pragma unroll
      for (int j = 0; j < 4; ++j)
        Cv[(size_t)(rbase + m * 16 + kgrp * 4 + j) * N + col] = f2bf(acc[m][n][j] + bv[n]);
    }
}

// ========= out-proj GEMM: 64x64 tile, BK=32, 1024 blocks = 4/CU (R10, passed) =========
__global__ __launch_bounds__(256, 4) void gemm_out3(
    const ushort* __restrict__ A, const ushort* __restrict__ Bt,
    const float* __restrict__ bias, float* __restrict__ Cv, int M, int N, int Kd) {
  const int gx = gridDim.x;  // 16
  const int nblk = gx * gridDim.y;
  const int fid = blockIdx.y * gx + blockIdx.x;
  const int nid = (fid & 7) * (nblk >> 3) + (fid >> 3);
  const int m0 = (nid / gx) * 64;
  const int n0 = (nid % gx) * 64;

  __shared__ ushort As[2][64 * 32];
  __shared__ ushort Bs[2][64 * 32];

  const int tid = threadIdx.x;
  const int wave = tid >> 6, lane = tid & 63;
  const int wmO = wave >> 1, wnO = wave & 1;
  const int lrow = lane & 15, kgrp = lane >> 4;

  const ushort* gA = A + (size_t)(m0 + (tid >> 2)) * Kd + (tid & 3) * 8;
  const ushort* gB = Bt + (size_t)(n0 + (tid >> 2)) * Kd + (tid & 3) * 8;

  auto stage = [&](int buf, int kt) {
    __builtin_amdgcn_global_load_lds((const AS1 void*)(gA + kt),
                                     (AS3 void*)(As[buf] + tid * 8), 16, 0, 0);
    __builtin_amdgcn_global_load_lds((const AS1 void*)(gB + kt),
                                     (AS3 void*)(Bs[buf] + tid * 8), 16, 0, 0);
  };

  f32x4 acc[2][2] = {};
  auto compute = [&](int buf) {
    short8 af[2], bfr[2];
#pragma unroll
    for (int mi = 0; mi < 2; ++mi)
      af[mi] = *(const short8*)(As[buf] + (wmO * 32 + mi * 16 + lrow) * 32 + kgrp * 8);
#pragma unroll
    for (int ni = 0; ni < 2; ++ni)
      bfr[ni] = *(const short8*)(Bs[buf] + (wnO * 32 + ni * 16 + lrow) * 32 + kgrp * 8);
#pragma unroll
    for (int mi = 0; mi < 2; ++mi)
#pragma unroll
      for (int ni = 0; ni < 2; ++ni)
        acc[mi][ni] = __builtin_amdgcn_mfma_f32_16x16x32_bf16(af[mi], bfr[ni], acc[mi][ni], 0, 0, 0);
  };

  const int nt = Kd >> 5;  // 32
  stage(0, 0);
  __syncthreads();
  int cur = 0;
  for (int it = 0; it < nt - 1; ++it) {
    stage(cur ^ 1, (it + 1) << 5);
    compute(cur);
    __syncthreads();
    cur ^= 1;
  }
  compute(cur);

  const int cbase = n0 + wnO * 32;
  const int rbase = m0 + wmO * 32;
  float bv[2];
#pragma unroll
  for (int ni = 0; ni < 2; ++ni) bv[ni] = bias[cbase + ni * 16 + lrow];
#pragma unroll
  for (int mi = 0; mi < 2; ++mi)
#pragma unroll
    for (int ni = 0; ni < 2; ++ni) {
      const int col = cbase + ni * 16 + lrow;
#pragma unroll
      for (int j = 0; j < 4; ++j)
        Cv[(size_t)(rbase + mi * 16 + kgrp * 4 + j) * N + col] = acc[mi][ni][j] + bv[ni];
    }
}

// ---------------- banded attention via residue-class MFMA flash (R10, passed) ----------------
__global__ __launch_bounds__(128) void banded_attn_mfma(
    const ushort* __restrict__ qp, const ushort* __restrict__ kp,
    const ushort* __restrict__ vp, ushort* __restrict__ ao) {
  __shared__ ushort Qs[32 * 128];
  __shared__ ushort Ks[96 * 128];
  __shared__ ushort Vs[112 * 128];
  __shared__ ushort Ps[2][16 * 104];
  __shared__ ushort Os[2][16 * 128];

  const int tid = threadIdx.x;
  const int wv = tid >> 6;
  const int lane = tid & 63;
  const int lrow = lane & 15, kgrp = lane >> 4;

  const int blk = blockIdx.x;
  const int chunk = blk & 63;
  const int h = (blk >> 6) & 7;
  const int b = blk >> 9;
  const int sh = h >> 1;
  const int dil = 1 << sh;
  const int Ld = LQ >> sh;
  const int rres = chunk >> (6 - sh);
  const int tile = chunk & ((64 >> sh) - 1);
  const int t0 = tile << 5;
  const int p0 = t0 - 32;

  const size_t headoff = (size_t)h * DH;
  const size_t bbase = (size_t)b * LQ * (NH * DH);

  const int srow = lane >> 4;
  const int sc = lane & 15;
  for (int it = wv; it < 60; it += 2) {
    int rbase, pstart;
    const ushort* g;
    ushort* ld;
    if (it < 8) {
      rbase = it * 4; pstart = t0; g = qp; ld = Qs;
    } else if (it < 32) {
      rbase = (it - 8) * 4; pstart = p0; g = kp; ld = Ks;
    } else {
      rbase = (it - 32) * 4; pstart = p0; g = vp; ld = Vs;
    }
    int row = rbase + srow;
    int key = (row ^ (row >> 3)) & 7;
    int cs = sc ^ key;
    int t = pstart + row;
    t = t < 0 ? 0 : (t >= Ld ? Ld - 1 : t);
    int l = rres + t * dil;
    const ushort* src = g + bbase + (size_t)l * (NH * DH) + headoff + cs * 8;
    __builtin_amdgcn_global_load_lds((const AS1 void*)src,
                                     (AS3 void*)(ld + rbase * 128), 16, 0, 0);
  }
  __syncthreads();

  const int iblk = wv << 4;
  f32x4 accs[5] = {};
#pragma unroll
  for (int ks = 0; ks < 4; ++ks) {
    const int qrow = iblk + lrow;
    const int qslot = (ks * 4 + kgrp) ^ ((qrow ^ (qrow >> 3)) & 7);
    short8 qf = *(const short8*)(Qs + qrow * 128 + qslot * 8);
#pragma unroll
    for (int t = 0; t < 5; ++t) {
      const int krow = (wv + t) * 16 + lrow;
      const int kslot = (ks * 4 + kgrp) ^ ((krow ^ (krow >> 3)) & 7);
      short8 kf = *(const short8*)(Ks + krow * 128 + kslot * 8);
      accs[t] = __builtin_amdgcn_mfma_f32_16x16x32_bf16(qf, kf, accs[t], 0, 0, 0);
    }
  }

  float dens[4];
#pragma unroll
  for (int j = 0; j < 4; ++j) {
    const int i_b = iblk + kgrp * 4 + j;
    float mj = -1e30f;
#pragma unroll
    for (int t = 0; t < 5; ++t) {
      const int jj = (wv + t) * 16 + lrow;
      const int p = p0 + jj;
      const bool ok = (jj >= i_b + 1) && (jj <= i_b + 64) && (p >= 0) && (p < Ld);
      float v = ok ? accs[t][j] : -1e30f;
      accs[t][j] = v;
      mj = fmaxf(mj, v);
    }
#pragma unroll
    for (int off = 1; off < 16; off <<= 1) mj = fmaxf(mj, __shfl_xor(mj, off));
    float dj = 0.f;
#pragma unroll
    for (int t = 0; t < 5; ++t) {
      float e = __expf(accs[t][j] - mj);
      accs[t][j] = e;
      dj += e;
    }
#pragma unroll
    for (int off = 1; off < 16; off <<= 1) dj += __shfl_xor(dj, off);
    dens[j] = dj;
  }

  ushort* Pw = Ps[wv];
#pragma unroll
  for (int j = 0; j < 4; ++j) {
    const int prow = kgrp * 4 + j;
#pragma unroll
    for (int t = 0; t < 5; ++t) Pw[prow * 104 + t * 16 + lrow] = f2bf(accs[t][j]);
    Pw[prow * 104 + 80 + lrow] = 0;
  }

  f32x4 accv[8] = {};
#pragma unroll
  for (int ks = 0; ks < 3; ++ks) {
    short8 pf = *(const short8*)(Pw + lrow * 104 + ks * 32 + kgrp * 8);
#pragma unroll
    for (int dt = 0; dt < 8; ++dt) {
      short8 vf;
#pragma unroll
      for (int rr = 0; rr < 8; ++rr) {
        const int vrow = iblk + ks * 32 + kgrp * 8 + rr;
        const int d = dt * 16 + lrow;
        const int slot = (d >> 3) ^ ((vrow ^ (vrow >> 3)) & 7);
        vf[rr] = (short)Vs[vrow * 128 + slot * 8 + (d & 7)];
      }
      accv[dt] = __builtin_amdgcn_mfma_f32_16x16x32_bf16(pf, vf, accv[dt], 0, 0, 0);
    }
  }

  ushort* Ow = Os[wv];
#pragma unroll
  for (int j = 0; j < 4; ++j) {
    const float inv = 1.f / dens[j];
    const int orow = kgrp * 4 + j;
#pragma unroll
    for (int dt = 0; dt < 8; ++dt)
      Ow[orow * 128 + dt * 16 + lrow] = f2bf(accv[dt][j] * inv);
  }
#pragma unroll
  for (int pass = 0; pass < 4; ++pass) {
    const int i_loc = pass * 4 + srow;
    const int tq = t0 + iblk + i_loc;
    const int l = rres + tq * dil;
    short8 vvv = *(const short8*)(Ow + i_loc * 128 + sc * 8);
    *(short8*)(ao + bbase + (size_t)l * (NH * DH) + headoff + sc * 8) = vvv;
  }
}

// ---------------- launch ----------------
extern "C" void kernel_launch(void* const* d_in, const int* in_sizes, int n_in,
                              void* d_out, int out_size, void* d_ws, size_t ws_size,
                              hipStream_t stream) {
  const float* q = (const float*)d_in[0];
  const float* k = (const float*)d_in[1];
  const float* v = (const float*)d_in[2];
  const float* Wq = (const float*)d_in[3];
  const float* bq = (const float*)d_in[4];
  const float* Wk = (const float*)d_in[5];
  const float* bk = (const float*)d_in[6];
  const float* Wv = (const float*)d_in[7];
  const float* bv = (const float*)d_in[8];
  const float* Wc = (const float*)d_in[9];
  const float* bc = (const float*)d_in[10];

  const size_t NIN = (size_t)NB * LQ * DMODEL;
  const size_t NW = (size_t)NH * DH * DMODEL;

  ushort* qin = (ushort*)d_ws;
  ushort* kin = qin + NIN;
  ushort* vin = kin + NIN;
  ushort* wqb = vin + NIN;
  ushort* wkb = wqb + NW;
  ushort* wvb = wkb + NW;
  ushort* wcb = wvb + NW;
  ushort* qp = wcb + NW;
  ushort* kp = qp + NIN;
  ushort* vp = kp + NIN;
  ushort* aob = vp + NIN;

  hipLaunchKernelGGL(cvt_all, dim3(2048), dim3(256), 0, stream,
                     (const float4*)q, (const float4*)k, (const float4*)v,
                     (const float4*)Wq, (const float4*)Wk, (const float4*)Wv,
                     (const float4*)Wc, (ushort4*)qin);

  dim3 g1(DMODEL / 256, (NB * LQ) / 256, 3);  // 192 blocks
  hipLaunchKernelGGL(gemm256_8p, g1, dim3(512), 0, stream,
                     qin, wqb, bq, qp,
                     kin, wkb, bk, kp,
                     vin, wvb, bv, vp,
                     NB * LQ, DMODEL, DMODEL);

  hipLaunchKernelGGL(banded_attn_mfma, dim3(NB * NH * 64), dim3(128), 0, stream,
                     qp, kp, vp, aob);

  dim3 g2(DMODEL / 64, (NB * LQ) / 64);  // 16 x 64 = 1024 blocks
  hipLaunchKernelGGL(gemm_out3, g2, dim3(256), 0, stream,
                     aob, wcb, bc, (float*)d_out, NB * LQ, DMODEL, DMODEL);
}

// Round 14
// 91.364 us; speedup vs baseline: 1.0803x; 1.0195x over previous
//
#include <hip/hip_runtime.h>
#include <hip/hip_bf16.h>
#include <stdint.h>

#define NB 2
#define LQ 2048
#define DMODEL 1024
#define NH 8
#define DH 128
#define KWIN 64

typedef __attribute__((ext_vector_type(8))) short short8;
typedef __attribute__((ext_vector_type(4))) float f32x4;

#define AS1 __attribute__((address_space(1)))
#define AS3 __attribute__((address_space(3)))

__device__ __forceinline__ ushort f2bf(float f) {
  uint u = __float_as_uint(f);
  return (ushort)((u + 0x7fffu + ((u >> 16) & 1u)) >> 16);
}

// ---------------- merged f32 -> bf16 conversion (7 arrays, one launch) ----------------
__global__ void cvt_all(const float4* __restrict__ q, const float4* __restrict__ k,
                        const float4* __restrict__ v, const float4* __restrict__ wq,
                        const float4* __restrict__ wk, const float4* __restrict__ wv,
                        const float4* __restrict__ wc, ushort4* __restrict__ dst) {
  const int n4in = (NB * LQ * DMODEL) / 4;   // 2^20
  const int n4w = (NH * DH * DMODEL) / 4;    // 2^18
  const int total = 3 * n4in + 4 * n4w;
  const int stride = gridDim.x * blockDim.x;
  for (int i = blockIdx.x * blockDim.x + threadIdx.x; i < total; i += stride) {
    const float4* src;
    int off;
    if (i < 3 * n4in) {
      const int r = i >> 20;
      off = i & (n4in - 1);
      src = (r == 0) ? q : ((r == 1) ? k : v);
    } else {
      const int j = i - 3 * n4in;
      const int r = j >> 18;
      off = j & (n4w - 1);
      src = (r == 0) ? wq : ((r == 1) ? wk : ((r == 2) ? wv : wc));
    }
    float4 x = src[off];
    dst[i] = make_ushort4(f2bf(x.x), f2bf(x.y), f2bf(x.z), f2bf(x.w));
  }
}

// ================= QKV GEMM: 256x256, BK=64, 8-phase (R8/R10, measured best) =================
__global__ __launch_bounds__(512, 2) void gemm256_8p(
    const ushort* __restrict__ A0p, const ushort* __restrict__ B0p,
    const float* __restrict__ c0, ushort* __restrict__ D0,
    const ushort* __restrict__ A1p, const ushort* __restrict__ B1p,
    const float* __restrict__ c1, ushort* __restrict__ D1,
    const ushort* __restrict__ A2p, const ushort* __restrict__ B2p,
    const float* __restrict__ c2, ushort* __restrict__ D2,
    int M, int N, int Kd) {
  const int gx = gridDim.x, gy = gridDim.y;
  const int nblk = gx * gy * gridDim.z;
  const int fid = (blockIdx.z * gy + blockIdx.y) * gx + blockIdx.x;
  const int nid = (fid & 7) * (nblk >> 3) + (fid >> 3);
  const int z = nid / (gx * gy);
  const int rem = nid % (gx * gy);
  const int m0 = (rem / gx) * 256;
  const int n0 = (rem % gx) * 256;

  const ushort* A = (z == 0) ? A0p : ((z == 1) ? A1p : A2p);
  const ushort* Bt = (z == 0) ? B0p : ((z == 1) ? B1p : B2p);
  const float* bias = (z == 0) ? c0 : ((z == 1) ? c1 : c2);
  ushort* Cv = (z == 0) ? D0 : ((z == 1) ? D1 : D2);

  __shared__ ushort LDS[2][32768];

  const int tid = threadIdx.x;
  const int wave = tid >> 6, lane = tid & 63;
  const int wm = wave >> 2, wn = wave & 3;
  const int lrow = lane & 15, kgrp = lane >> 4;

  int offA[2][2], offB[2][2];
#pragma unroll
  for (int u = 0; u < 2; ++u)
#pragma unroll
    for (int j = 0; j < 2; ++j) {
      const int idx = j * 512 + tid;
      const int s = idx >> 3, c = idx & 7;
      const int cs = c ^ (s & 7);
      const int rA = ((s >> 6) << 7) | (u << 6) | (s & 63);
      const int rB = ((s >> 5) << 6) | (u << 5) | (s & 31);
      offA[u][j] = (m0 + rA) * Kd + cs * 8;
      offB[u][j] = (n0 + rB) * Kd + cs * 8;
    }

  auto STAGEA = [&](int bufb, int u, int T) {
    ushort* dst = &LDS[bufb][u * 8192];
#pragma unroll
    for (int j = 0; j < 2; ++j)
      __builtin_amdgcn_global_load_lds((const AS1 void*)(A + offA[u][j] + T * 64),
                                       (AS3 void*)(dst + (j * 512 + tid) * 8), 16, 0, 0);
  };
  auto STAGEB = [&](int bufb, int u, int T) {
    ushort* dst = &LDS[bufb][16384 + u * 8192];
#pragma unroll
    for (int j = 0; j < 2; ++j)
      __builtin_amdgcn_global_load_lds((const AS1 void*)(Bt + offB[u][j] + T * 64),
                                       (AS3 void*)(dst + (j * 512 + tid) * 8), 16, 0, 0);
  };

  const int sAb = (wm * 64 + lrow) * 64;
  const int sBb = (wn * 32 + lrow) * 64;
  int xk[2];
#pragma unroll
  for (int ks = 0; ks < 2; ++ks) xk[ks] = ((ks * 4 + kgrp) ^ (lrow & 7)) * 8;

  short8 af[4][2], bf[2][2][2];
  f32x4 acc[8][4] = {};

  auto RDA = [&](int bufb, int mh) {
#pragma unroll
    for (int mi = 0; mi < 4; ++mi)
#pragma unroll
      for (int ks = 0; ks < 2; ++ks)
        af[mi][ks] = *(const short8*)(&LDS[bufb][mh * 8192 + sAb + mi * 1024 + xk[ks]]);
  };
  auto RDB = [&](int bufb, int nh) {
#pragma unroll
    for (int ni = 0; ni < 2; ++ni)
#pragma unroll
      for (int ks = 0; ks < 2; ++ks)
        bf[nh][ni][ks] =
            *(const short8*)(&LDS[bufb][16384 + nh * 8192 + sBb + ni * 1024 + xk[ks]]);
  };
  auto MM = [&](int mh, int nh) {
    __builtin_amdgcn_s_setprio(1);
#pragma unroll
    for (int mi = 0; mi < 4; ++mi)
#pragma unroll
      for (int ni = 0; ni < 2; ++ni)
#pragma unroll
        for (int ks = 0; ks < 2; ++ks)
          acc[mh * 4 + mi][nh * 2 + ni] = __builtin_amdgcn_mfma_f32_16x16x32_bf16(
              af[mi][ks], bf[nh][ni][ks], acc[mh * 4 + mi][nh * 2 + ni], 0, 0, 0);
    __builtin_amdgcn_s_setprio(0);
  };

#define LGKM0()                                        \
  asm volatile("s_waitcnt lgkmcnt(0)" ::: "memory");   \
  __builtin_amdgcn_sched_barrier(0)
#define BAR() __builtin_amdgcn_s_barrier()

  const int NKT = Kd >> 6;
  const int NIT = NKT >> 1;

  STAGEA(0, 0, 0); STAGEB(0, 0, 0); STAGEA(0, 1, 0); STAGEB(0, 1, 0);
  STAGEA(1, 0, 1); STAGEB(1, 0, 1);
  asm volatile("s_waitcnt vmcnt(4)" ::: "memory");
  __builtin_amdgcn_sched_barrier(0);
  BAR();

  for (int i = 0; i < NIT; ++i) {
    const int ta = 2 * i, tb = ta + 1;
    const bool sA = (ta + 2) < NKT, sB = (tb + 2) < NKT;
    RDA(0, 0); RDB(0, 0);
    STAGEA(1, 1, tb);
    BAR(); LGKM0(); MM(0, 0); BAR();
    RDB(0, 1);
    STAGEB(1, 1, tb);
    BAR(); LGKM0(); MM(0, 1); BAR();
    RDA(0, 1);
    if (sA) STAGEA(0, 0, ta + 2);
    BAR(); LGKM0(); MM(1, 0); BAR();
    if (sA) STAGEB(0, 0, ta + 2);
    MM(1, 1);
    if (sA) asm volatile("s_waitcnt vmcnt(4)" ::: "memory");
    else    asm volatile("s_waitcnt vmcnt(0)" ::: "memory");
    __builtin_amdgcn_sched_barrier(0);
    BAR();
    RDA(1, 0); RDB(1, 0);
    if (sA) STAGEA(0, 1, ta + 2);
    BAR(); LGKM0(); MM(0, 0); BAR();
    RDB(1, 1);
    if (sA) STAGEB(0, 1, ta + 2);
    BAR(); LGKM0(); MM(0, 1); BAR();
    RDA(1, 1);
    if (sB) STAGEA(1, 0, tb + 2);
    BAR(); LGKM0(); MM(1, 0); BAR();
    if (sB) STAGEB(1, 0, tb + 2);
    MM(1, 1);
    if (sB) asm volatile("s_waitcnt vmcnt(4)" ::: "memory");
    else    asm volatile("s_waitcnt vmcnt(0)" ::: "memory");
    __builtin_amdgcn_sched_barrier(0);
    BAR();
  }
#undef LGKM0
#undef BAR

  const int cbase = n0 + wn * 64;
  const int rbase = m0 + wm * 128;
  float bv[4];
#pragma unroll
  for (int n = 0; n < 4; ++n) bv[n] = bias[cbase + n * 16 + lrow];
#pragma unroll
  for (int m = 0; m < 8; ++m)
#pragma unroll
    for (int n = 0; n < 4; ++n) {
      const int col = cbase + n * 16 + lrow;
#pragma unroll
      for (int j = 0; j < 4; ++j)
        Cv[(size_t)(rbase + m * 16 + kgrp * 4 + j) * N + col] = f2bf(acc[m][n][j] + bv[n]);
    }
}

// ===== out-proj GEMM: 64x64 tile, BK=64 (16 iters), 1024 blocks = 4/CU, swizzled LDS =====
// Halves the drain-barrier count vs BK=32. 128B row stride needs the proven gemm256_8p
// swizzle: staged source cs = c^(row&7); read slot (ks*4+kgrp)^(lrow&7) -> 2-way (free).
__global__ __launch_bounds__(256, 4) void gemm_out4(
    const ushort* __restrict__ A, const ushort* __restrict__ Bt,
    const float* __restrict__ bias, float* __restrict__ Cv, int M, int N, int Kd) {
  const int gx = gridDim.x;  // 16
  const int nblk = gx * gridDim.y;
  const int fid = blockIdx.y * gx + blockIdx.x;
  const int nid = (fid & 7) * (nblk >> 3) + (fid >> 3);
  const int m0 = (nid / gx) * 64;
  const int n0 = (nid % gx) * 64;

  __shared__ ushort As[2][64 * 64];  // 8 KB each
  __shared__ ushort Bs[2][64 * 64];

  const int tid = threadIdx.x;
  const int wave = tid >> 6, lane = tid & 63;
  const int wmO = wave >> 1, wnO = wave & 1;
  const int lrow = lane & 15, kgrp = lane >> 4;

  // staging: chunk idx = j*256+tid; row = idx>>3, c = idx&7, source chunk cs = c^(row&7)
  int offA[2], offB[2];
#pragma unroll
  for (int j = 0; j < 2; ++j) {
    const int idx = j * 256 + tid;
    const int row = idx >> 3, c = idx & 7;
    const int cs = c ^ (row & 7);
    offA[j] = (m0 + row) * Kd + cs * 8;
    offB[j] = (n0 + row) * Kd + cs * 8;
  }

  auto stage = [&](int buf, int kt) {
#pragma unroll
    for (int j = 0; j < 2; ++j) {
      __builtin_amdgcn_global_load_lds((const AS1 void*)(A + offA[j] + kt),
                                       (AS3 void*)(As[buf] + (j * 256 + tid) * 8), 16, 0, 0);
      __builtin_amdgcn_global_load_lds((const AS1 void*)(Bt + offB[j] + kt),
                                       (AS3 void*)(Bs[buf] + (j * 256 + tid) * 8), 16, 0, 0);
    }
  };

  int xk[2];
#pragma unroll
  for (int ks = 0; ks < 2; ++ks) xk[ks] = ((ks * 4 + kgrp) ^ (lrow & 7)) * 8;

  f32x4 acc[2][2] = {};
  auto compute = [&](int buf) {
    short8 af[2][2], bfr[2][2];
#pragma unroll
    for (int mi = 0; mi < 2; ++mi)
#pragma unroll
      for (int ks = 0; ks < 2; ++ks)
        af[mi][ks] = *(const short8*)(As[buf] + (wmO * 32 + mi * 16 + lrow) * 64 + xk[ks]);
#pragma unroll
    for (int ni = 0; ni < 2; ++ni)
#pragma unroll
      for (int ks = 0; ks < 2; ++ks)
        bfr[ni][ks] = *(const short8*)(Bs[buf] + (wnO * 32 + ni * 16 + lrow) * 64 + xk[ks]);
#pragma unroll
    for (int mi = 0; mi < 2; ++mi)
#pragma unroll
      for (int ni = 0; ni < 2; ++ni)
#pragma unroll
        for (int ks = 0; ks < 2; ++ks)
          acc[mi][ni] = __builtin_amdgcn_mfma_f32_16x16x32_bf16(af[mi][ks], bfr[ni][ks],
                                                                acc[mi][ni], 0, 0, 0);
  };

  const int nt = Kd >> 6;  // 16
  stage(0, 0);
  __syncthreads();
  int cur = 0;
  for (int it = 0; it < nt - 1; ++it) {
    stage(cur ^ 1, (it + 1) << 6);
    compute(cur);
    __syncthreads();
    cur ^= 1;
  }
  compute(cur);

  const int cbase = n0 + wnO * 32;
  const int rbase = m0 + wmO * 32;
  float bv[2];
#pragma unroll
  for (int ni = 0; ni < 2; ++ni) bv[ni] = bias[cbase + ni * 16 + lrow];
#pragma unroll
  for (int mi = 0; mi < 2; ++mi)
#pragma unroll
    for (int ni = 0; ni < 2; ++ni) {
      const int col = cbase + ni * 16 + lrow;
#pragma unroll
      for (int j = 0; j < 4; ++j)
        Cv[(size_t)(rbase + mi * 16 + kgrp * 4 + j) * N + col] = acc[mi][ni][j] + bv[ni];
    }
}

// ---------------- banded attention via residue-class MFMA flash (R10, passed) ----------------
__global__ __launch_bounds__(128) void banded_attn_mfma(
    const ushort* __restrict__ qp, const ushort* __restrict__ kp,
    const ushort* __restrict__ vp, ushort* __restrict__ ao) {
  __shared__ ushort Qs[32 * 128];
  __shared__ ushort Ks[96 * 128];
  __shared__ ushort Vs[112 * 128];
  __shared__ ushort Ps[2][16 * 104];
  __shared__ ushort Os[2][16 * 128];

  const int tid = threadIdx.x;
  const int wv = tid >> 6;
  const int lane = tid & 63;
  const int lrow = lane & 15, kgrp = lane >> 4;

  const int blk = blockIdx.x;
  const int chunk = blk & 63;
  const int h = (blk >> 6) & 7;
  const int b = blk >> 9;
  const int sh = h >> 1;
  const int dil = 1 << sh;
  const int Ld = LQ >> sh;
  const int rres = chunk >> (6 - sh);
  const int tile = chunk & ((64 >> sh) - 1);
  const int t0 = tile << 5;
  const int p0 = t0 - 32;

  const size_t headoff = (size_t)h * DH;
  const size_t bbase = (size_t)b * LQ * (NH * DH);

  const int srow = lane >> 4;
  const int sc = lane & 15;
  for (int it = wv; it < 60; it += 2) {
    int rbase, pstart;
    const ushort* g;
    ushort* ld;
    if (it < 8) {
      rbase = it * 4; pstart = t0; g = qp; ld = Qs;
    } else if (it < 32) {
      rbase = (it - 8) * 4; pstart = p0; g = kp; ld = Ks;
    } else {
      rbase = (it - 32) * 4; pstart = p0; g = vp; ld = Vs;
    }
    int row = rbase + srow;
    int key = (row ^ (row >> 3)) & 7;
    int cs = sc ^ key;
    int t = pstart + row;
    t = t < 0 ? 0 : (t >= Ld ? Ld - 1 : t);
    int l = rres + t * dil;
    const ushort* src = g + bbase + (size_t)l * (NH * DH) + headoff + cs * 8;
    __builtin_amdgcn_global_load_lds((const AS1 void*)src,
                                     (AS3 void*)(ld + rbase * 128), 16, 0, 0);
  }
  __syncthreads();

  const int iblk = wv << 4;
  f32x4 accs[5] = {};
#pragma unroll
  for (int ks = 0; ks < 4; ++ks) {
    const int qrow = iblk + lrow;
    const int qslot = (ks * 4 + kgrp) ^ ((qrow ^ (qrow >> 3)) & 7);
    short8 qf = *(const short8*)(Qs + qrow * 128 + qslot * 8);
#pragma unroll
    for (int t = 0; t < 5; ++t) {
      const int krow = (wv + t) * 16 + lrow;
      const int kslot = (ks * 4 + kgrp) ^ ((krow ^ (krow >> 3)) & 7);
      short8 kf = *(const short8*)(Ks + krow * 128 + kslot * 8);
      accs[t] = __builtin_amdgcn_mfma_f32_16x16x32_bf16(qf, kf, accs[t], 0, 0, 0);
    }
  }

  float dens[4];
#pragma unroll
  for (int j = 0; j < 4; ++j) {
    const int i_b = iblk + kgrp * 4 + j;
    float mj = -1e30f;
#pragma unroll
    for (int t = 0; t < 5; ++t) {
      const int jj = (wv + t) * 16 + lrow;
      const int p = p0 + jj;
      const bool ok = (jj >= i_b + 1) && (jj <= i_b + 64) && (p >= 0) && (p < Ld);
      float v = ok ? accs[t][j] : -1e30f;
      accs[t][j] = v;
      mj = fmaxf(mj, v);
    }
#pragma unroll
    for (int off = 1; off < 16; off <<= 1) mj = fmaxf(mj, __shfl_xor(mj, off));
    float dj = 0.f;
#pragma unroll
    for (int t = 0; t < 5; ++t) {
      float e = __expf(accs[t][j] - mj);
      accs[t][j] = e;
      dj += e;
    }
#pragma unroll
    for (int off = 1; off < 16; off <<= 1) dj += __shfl_xor(dj, off);
    dens[j] = dj;
  }

  ushort* Pw = Ps[wv];
#pragma unroll
  for (int j = 0; j < 4; ++j) {
    const int prow = kgrp * 4 + j;
#pragma unroll
    for (int t = 0; t < 5; ++t) Pw[prow * 104 + t * 16 + lrow] = f2bf(accs[t][j]);
    Pw[prow * 104 + 80 + lrow] = 0;
  }

  f32x4 accv[8] = {};
#pragma unroll
  for (int ks = 0; ks < 3; ++ks) {
    short8 pf = *(const short8*)(Pw + lrow * 104 + ks * 32 + kgrp * 8);
#pragma unroll
    for (int dt = 0; dt < 8; ++dt) {
      short8 vf;
#pragma unroll
      for (int rr = 0; rr < 8; ++rr) {
        const int vrow = iblk + ks * 32 + kgrp * 8 + rr;
        const int d = dt * 16 + lrow;
        const int slot = (d >> 3) ^ ((vrow ^ (vrow >> 3)) & 7);
        vf[rr] = (short)Vs[vrow * 128 + slot * 8 + (d & 7)];
      }
      accv[dt] = __builtin_amdgcn_mfma_f32_16x16x32_bf16(pf, vf, accv[dt], 0, 0, 0);
    }
  }

  ushort* Ow = Os[wv];
#pragma unroll
  for (int j = 0; j < 4; ++j) {
    const float inv = 1.f / dens[j];
    const int orow = kgrp * 4 + j;
#pragma unroll
    for (int dt = 0; dt < 8; ++dt)
      Ow[orow * 128 + dt * 16 + lrow] = f2bf(accv[dt][j] * inv);
  }
#pragma unroll
  for (int pass = 0; pass < 4; ++pass) {
    const int i_loc = pass * 4 + srow;
    const int tq = t0 + iblk + i_loc;
    const int l = rres + tq * dil;
    short8 vvv = *(const short8*)(Ow + i_loc * 128 + sc * 8);
    *(short8*)(ao + bbase + (size_t)l * (NH * DH) + headoff + sc * 8) = vvv;
  }
}

// ---------------- launch ----------------
extern "C" void kernel_launch(void* const* d_in, const int* in_sizes, int n_in,
                              void* d_out, int out_size, void* d_ws, size_t ws_size,
                              hipStream_t stream) {
  const float* q = (const float*)d_in[0];
  const float* k = (const float*)d_in[1];
  const float* v = (const float*)d_in[2];
  const float* Wq = (const float*)d_in[3];
  const float* bq = (const float*)d_in[4];
  const float* Wk = (const float*)d_in[5];
  const float* bk = (const float*)d_in[6];
  const float* Wv = (const float*)d_in[7];
  const float* bv = (const float*)d_in[8];
  const float* Wc = (const float*)d_in[9];
  const float* bc = (const float*)d_in[10];

  const size_t NIN = (size_t)NB * LQ * DMODEL;
  const size_t NW = (size_t)NH * DH * DMODEL;

  ushort* qin = (ushort*)d_ws;
  ushort* kin = qin + NIN;
  ushort* vin = kin + NIN;
  ushort* wqb = vin + NIN;
  ushort* wkb = wqb + NW;
  ushort* wvb = wkb + NW;
  ushort* wcb = wvb + NW;
  ushort* qp = wcb + NW;
  ushort* kp = qp + NIN;
  ushort* vp = kp + NIN;
  ushort* aob = vp + NIN;

  hipLaunchKernelGGL(cvt_all, dim3(2048), dim3(256), 0, stream,
                     (const float4*)q, (const float4*)k, (const float4*)v,
                     (const float4*)Wq, (const float4*)Wk, (const float4*)Wv,
                     (const float4*)Wc, (ushort4*)qin);

  dim3 g1(DMODEL / 256, (NB * LQ) / 256, 3);  // 192 blocks
  hipLaunchKernelGGL(gemm256_8p, g1, dim3(512), 0, stream,
                     qin, wqb, bq, qp,
                     kin, wkb, bk, kp,
                     vin, wvb, bv, vp,
                     NB * LQ, DMODEL, DMODEL);

  hipLaunchKernelGGL(banded_attn_mfma, dim3(NB * NH * 64), dim3(128), 0, stream,
                     qp, kp, vp, aob);

  dim3 g2(DMODEL / 64, (NB * LQ) / 64);  // 16 x 64 = 1024 blocks
  hipLaunchKernelGGL(gemm_out4, g2, dim3(256), 0, stream,
                     aob, wcb, bc, (float*)d_out, NB * LQ, DMODEL, DMODEL);
}